// Round 11
// baseline (508.374 us; speedup 1.0000x reference)
//
#include <hip/hip_runtime.h>
#include <hip/hip_bf16.h>
#include <math.h>
#include <stdint.h>

#define NO_N 100000
#define NR_N 1000
#define E_N  1000000
#define SB     250      // scatter blocks
#define SCHUNK 4000     // edges per scatter block (SB*SCHUNK == E_N)
#define KVP_TILES 1563  // ceil(NO_N/64)
#define KVP_BLKS 1024
#define MAXTILES 17008  // > NR_N + E_N/64
#define TREC_BLKS ((MAXTILES + 1023) / 1024)

typedef short bf16x8 __attribute__((ext_vector_type(8)));
typedef float floatx4 __attribute__((ext_vector_type(4)));

__device__ __forceinline__ unsigned short bfu(float x) {
    union { __hip_bfloat16 h; unsigned short u; } c;
    c.h = __float2bfloat16(x);
    return c.u;
}
__device__ __forceinline__ float bflo(unsigned int u) {
    return __uint_as_float(u << 16);
}
__device__ __forceinline__ float bfhi(unsigned int u) {
    return __uint_as_float(u & 0xffff0000u);
}

// ---------------------------------------------------------------------------
// fat front-end: [0,250) prep_rider | 250 b1eff + W1a^T table + done-reset |
// [251,251+KVP_BLKS) kvp | then SB hist2 blocks.  (round-6 proven form)
// ---------------------------------------------------------------------------
__global__ __launch_bounds__(256) void k_front(
    const float* __restrict__ xr,
    const float* __restrict__ Wq, const float* __restrict__ bq,
    const float* __restrict__ Wskip, const float* __restrict__ bskip,
    const float* __restrict__ We,
    float* __restrict__ q, float* __restrict__ skip, float* __restrict__ t,
    const float* __restrict__ W1, const float* __restrict__ b1,
    const float* __restrict__ omega, float* __restrict__ b1eff,
    unsigned short* __restrict__ w1t,
    const float* __restrict__ x,
    const float* __restrict__ Wk, const float* __restrict__ bk,
    const float* __restrict__ Wv, const float* __restrict__ bv,
    const float* __restrict__ Wp, const float* __restrict__ bp,
    unsigned short* __restrict__ kb, unsigned short* __restrict__ vb,
    unsigned short* __restrict__ pb,
    const int* __restrict__ ridx, int* __restrict__ ghist,
    int* __restrict__ done)
{
    __shared__ __align__(16) char smem[9216];
    const int tid = threadIdx.x;
    const int b = blockIdx.x;

    if (b < 250) {
        // ---------------- prep_rider ----------------
        float* sx = (float*)smem;            // [4][32]
        float* sq = sx + 128;                // [4][64]
        int rbase = b * 4;
        if (tid < 128) {
            int rl = tid >> 5, d = tid & 31;
            sx[rl * 32 + d] = xr[(rbase + rl) * 32 + d];
        }
        __syncthreads();
        int rl = tid >> 6, h = tid & 63;
        int r = rbase + rl;
        float aq = bq[h], as = bskip[h];
        #pragma unroll 4
        for (int d = 0; d < 32; ++d) {
            float xv = sx[rl * 32 + d];
            aq += xv * Wq[d * 64 + h];
            as += xv * Wskip[d * 64 + h];
        }
        sq[rl * 64 + h] = aq;
        q[r * 64 + h] = aq;
        skip[r * 64 + h] = as;
        __syncthreads();
        if (tid < 16) {
            int rl2 = tid >> 2, d = tid & 3;
            float acc = 0.f;
            for (int hh = 0; hh < 64; ++hh)
                acc += We[d * 64 + hh] * sq[rl2 * 64 + hh];
            t[(rbase + rl2) * 4 + d] = acc;
        }
    } else if (b == 250) {
        // ---------------- b1eff + W1a^T bf16 + k_mid done-counter reset ----
        if (tid == 0) done[0] = 0;           // graph-replay-safe re-zero
        if (tid < 128) {
            float acc = b1[tid];
            #pragma unroll 4
            for (int j = 0; j < 32; ++j)
                acc += omega[j] * W1[(128 + j) * 128 + tid];
            b1eff[tid] = acc;
        }
        // w1t[n*64+k] = bf16(W1[k*128+n]) for k<64 (the oe rows), n<128
        for (int idx = tid; idx < 64 * 128; idx += 256) {
            int n = idx >> 6, k = idx & 63;
            w1t[idx] = bfu(W1[k * 128 + n]);
        }
    } else if (b < 251 + KVP_BLKS) {
        // ---------------- kvp (bf16 MFMA) ----------------
        unsigned short* sX = (unsigned short*)smem;   // 64*72
        const int wave = tid >> 6, lane = tid & 63;
        const int l15 = lane & 15, quad = lane >> 4;

        bf16x8 bfr[3][2];
        float bias[3];
        unsigned short* outT[3];
        int colc[3];
        #pragma unroll
        for (int ct = 0; ct < 3; ++ct) {
            int n = wave * 48 + ct * 16 + l15;
            int table = n >> 6, c = n & 63;
            const float* W  = (table == 0) ? Wk : (table == 1) ? Wv : Wp;
            const float* bb = (table == 0) ? bk : (table == 1) ? bv : bp;
            bias[ct] = bb[c];
            colc[ct] = c;
            outT[ct] = (table == 0) ? kb : (table == 1) ? vb : pb;
            #pragma unroll
            for (int kf = 0; kf < 2; ++kf) {
                bf16x8 f;
                #pragma unroll
                for (int j = 0; j < 8; ++j)
                    f[j] = (short)bfu(W[(size_t)(kf * 32 + quad * 8 + j) * 64 + c]);
                bfr[ct][kf] = f;
            }
        }

        const int srl = tid >> 2;
        const int sqt = (tid & 3) * 16;

        for (int tile = b - 251; tile < KVP_TILES; tile += KVP_BLKS) {
            int rowbase = tile * 64;
            {
                int row = rowbase + srl;
                unsigned short* dst = sX + srl * 72 + sqt;
                if (row < NO_N) {
                    const float4* src = (const float4*)(x + (size_t)row * 64 + sqt);
                    #pragma unroll
                    for (int i = 0; i < 4; ++i) {
                        float4 a = src[i];
                        ushort4 u = { bfu(a.x), bfu(a.y), bfu(a.z), bfu(a.w) };
                        *(ushort4*)(dst + i * 4) = u;
                    }
                } else {
                    ushort4 z = {0, 0, 0, 0};
                    #pragma unroll
                    for (int i = 0; i < 4; ++i) *(ushort4*)(dst + i * 4) = z;
                }
            }
            __syncthreads();

            floatx4 acc[4][3];
            #pragma unroll
            for (int rt = 0; rt < 4; ++rt)
                #pragma unroll
                for (int ct = 0; ct < 3; ++ct)
                    acc[rt][ct] = (floatx4){bias[ct], bias[ct], bias[ct], bias[ct]};

            #pragma unroll
            for (int rt = 0; rt < 4; ++rt) {
                const unsigned short* ar = sX + (size_t)(rt * 16 + l15) * 72 + quad * 8;
                bf16x8 a0 = *(const bf16x8*)(ar);
                bf16x8 a1 = *(const bf16x8*)(ar + 32);
                #pragma unroll
                for (int ct = 0; ct < 3; ++ct) {
                    floatx4 c = acc[rt][ct];
                    c = __builtin_amdgcn_mfma_f32_16x16x32_bf16(a0, bfr[ct][0], c, 0, 0, 0);
                    c = __builtin_amdgcn_mfma_f32_16x16x32_bf16(a1, bfr[ct][1], c, 0, 0, 0);
                    acc[rt][ct] = c;
                }
            }

            #pragma unroll
            for (int rt = 0; rt < 4; ++rt) {
                int rb = rowbase + rt * 16 + quad * 4;
                #pragma unroll
                for (int ct = 0; ct < 3; ++ct) {
                    unsigned short* o = outT[ct];
                    size_t cbase = colc[ct];
                    #pragma unroll
                    for (int g = 0; g < 4; ++g) {
                        int row = rb + g;
                        if (row < NO_N)
                            o[(size_t)row * 64 + cbase] = bfu(acc[rt][ct][g]);
                    }
                }
            }
            __syncthreads();
        }
    } else {
        // ---------------- hist2 ----------------
        int* hc = (int*)smem;                 // [NR_N]
        int hb = b - (251 + KVP_BLKS);
        for (int i = tid; i < NR_N; i += 256) hc[i] = 0;
        __syncthreads();
        int s = hb * SCHUNK;
        for (int i = s + tid; i < s + SCHUNK; i += 256)
            atomicAdd(&hc[ridx[i]], 1);
        __syncthreads();
        for (int i = tid; i < NR_N; i += 256)
            ghist[i * SB + hb] = hc[i];
    }
}

// ---------------------------------------------------------------------------
// MERGED colscan + rider-scan (last-block-done pattern).  Each block scans
// one rider's ghist row (phase 1); the 1000th block to finish additionally
// runs the rider-level scan producing offsets + tilestart (phase 2).
// Device-scope fences around the done-counter per Guideline 16; `done` is
// re-zeroed by k_front each launch.  Saves 1 launch + gap vs split kernels.
// ---------------------------------------------------------------------------
__global__ __launch_bounds__(1024) void k_mid(
    const int* __restrict__ ghist, int* __restrict__ gpre,
    int* __restrict__ counts, int* __restrict__ offsets,
    int* __restrict__ tilestart, int* __restrict__ done)
{
    __shared__ int s[1024];
    __shared__ int lastFlag;
    const int tid = threadIdx.x, r = blockIdx.x;

    // ---- phase 1: colscan of ghist[r][.] ----
    int v = (tid < SB) ? ghist[r * SB + tid] : 0;
    s[tid] = v;
    __syncthreads();
    for (int off = 1; off < 1024; off <<= 1) {
        int tv = (tid >= off) ? s[tid - off] : 0;
        __syncthreads();
        s[tid] += tv;
        __syncthreads();
    }
    if (tid < SB) gpre[r * SB + tid] = s[tid] - v;
    if (tid == 1023) counts[r] = s[1023];

    // ---- completion detection ----
    __threadfence();                       // release our counts/gpre writes
    if (tid == 0) {
        int old = atomicAdd(done, 1);
        lastFlag = (old == NR_N - 1);
    }
    __syncthreads();
    if (!lastFlag) return;
    __threadfence();                       // acquire all blocks' writes

    // ---- phase 2 (last block only): rider scan -> offsets, tilestart ----
    int c = (tid < NR_N) ? counts[tid] : 0;
    s[tid] = c;
    __syncthreads();
    for (int off = 1; off < 1024; off <<= 1) {
        int tv = (tid >= off) ? s[tid - off] : 0;
        __syncthreads();
        s[tid] += tv;
        __syncthreads();
    }
    if (tid < NR_N) offsets[tid] = s[tid] - c;
    if (tid == NR_N - 1) offsets[NR_N] = s[tid];
    __syncthreads();
    int tc = (tid < NR_N) ? ((c + 63) >> 6) : 0;
    s[tid] = tc;
    __syncthreads();
    for (int off = 1; off < 1024; off <<= 1) {
        int tv = (tid >= off) ? s[tid - off] : 0;
        __syncthreads();
        s[tid] += tv;
        __syncthreads();
    }
    if (tid < NR_N) tilestart[tid] = s[tid] - tc;
    if (tid == NR_N - 1) tilestart[NR_N] = s[tid];
}

// ---------------------------------------------------------------------------
// scatter (round-6 staged form: kills the 2.5x write amplification) + trec
// fill appended as extra blocks [SB, SB+TREC_BLKS) — both depend only on
// k_mid's outputs, so they share one launch.
// ---------------------------------------------------------------------------
__global__ __launch_bounds__(1024) void k_scatter2(
    const int* __restrict__ ridx, const int* __restrict__ oidx,
    const float* __restrict__ ea, const float* __restrict__ t,
    const int* __restrict__ offsets, const int* __restrict__ gpre,
    const int* __restrict__ ghist,
    int4* __restrict__ spack, int* __restrict__ so, int* __restrict__ rank,
    const int* __restrict__ tilestart, int4* __restrict__ trec)
{
    const int tid = threadIdx.x, b = blockIdx.x;

    if (b >= SB) {
        // ---------------- trec fill (binary search, L2-hot) ----------------
        int nt = tilestart[NR_N];
        int tt = (b - SB) * 1024 + tid;
        if (tt >= nt) return;
        int lo = 0, hi = NR_N - 1;
        while (lo < hi) {             // largest r with tilestart[r] <= tt
            int mid = (lo + hi + 1) >> 1;
            if (tilestart[mid] <= tt) lo = mid; else hi = mid - 1;
        }
        trec[tt] = make_int4(lo, offsets[lo] + ((tt - tilestart[lo]) << 6),
                             offsets[lo + 1], 0);
        return;
    }

    __shared__ int stmp[1024];          // scan temp
    __shared__ int lpre[NR_N];          // block-local exclusive prefix
    __shared__ int lcur[NR_N];          // per-rider cursor (from 0)
    __shared__ int gbase[NR_N];         // offsets[r] + gpre[r][b]
    __shared__ __align__(16) int4 sbuf[SCHUNK];   // 64 KB staging
    __shared__ int spos[SCHUNK];        // global position per lpos

    // ---- scan ghist[.][b] -> lpre; init lcur, gbase ----
    int v = (tid < NR_N) ? ghist[tid * SB + b] : 0;
    stmp[tid] = v;
    __syncthreads();
    for (int off = 1; off < 1024; off <<= 1) {
        int tv = (tid >= off) ? stmp[tid - off] : 0;
        __syncthreads();
        stmp[tid] += tv;
        __syncthreads();
    }
    if (tid < NR_N) {
        lpre[tid] = stmp[tid] - v;      // exclusive
        lcur[tid] = 0;
        gbase[tid] = offsets[tid] + gpre[tid * SB + b];
    }
    __syncthreads();

    // ---- compute + stage ----
    int s = b * SCHUNK;
    for (int i = s + tid; i < s + SCHUNK; i += 1024) {
        int r = ridx[i];
        int o = oidx[i];
        float4 e4 = *(const float4*)(ea + (size_t)i * 4);
        float4 t4 = *(const float4*)(t + r * 4);
        float h = e4.x * t4.x + e4.y * t4.y + e4.z * t4.z + e4.w * t4.w;
        int old = atomicAdd(&lcur[r], 1);
        int lpos = lpre[r] + old;
        int gp = gbase[r] + old;
        int4 pk;
        pk.x = o;
        pk.y = __float_as_int(h);
        pk.z = (int)((unsigned)bfu(e4.x) | ((unsigned)bfu(e4.y) << 16));
        pk.w = (int)((unsigned)bfu(e4.z) | ((unsigned)bfu(e4.w) << 16));
        sbuf[lpos] = pk;
        spos[lpos] = gp;
        rank[i] = gp;                   // coalesced in i
    }
    __syncthreads();

    // ---- ordered flush: consecutive lpos -> consecutive gp per group ----
    for (int l = tid; l < SCHUNK; l += 1024) {
        int4 pk = sbuf[l];
        int gp = spos[l];
        spack[gp] = pk;
        so[gp] = pk.x;
    }
}

// ---------------------------------------------------------------------------
// rider embedding + fused Br (r7 form: 4-way ILP chains, 512 thr, 64 VGPR —
// exactly at the 8-waves/SIMD cliff; do not add registers).
// ---------------------------------------------------------------------------
__global__ __launch_bounds__(512) void k_rider(
    const int* __restrict__ offsets, const int4* __restrict__ spack,
    const float* __restrict__ q,
    const unsigned short* __restrict__ kb, const unsigned short* __restrict__ vb,
    const float* __restrict__ We, const float* __restrict__ skip,
    const float* __restrict__ W1, const float* __restrict__ b1eff,
    unsigned short* __restrict__ embb, float* __restrict__ Br)
{
    __shared__ float sQ[64];
    __shared__ int2 sOX[8][64];
    __shared__ float rv[8][64];
    __shared__ float re4[8][4];
    __shared__ float rd[8];

    int r = blockIdx.x;
    int wave = threadIdx.x >> 6, lane = threadIdx.x & 63;
    if (threadIdx.x < 64) sQ[threadIdx.x] = q[r * 64 + threadIdx.x];
    __syncthreads();

    int beg = offsets[r], end = offsets[r + 1];
    int cnt = end - beg;
    int chunk = (cnt + 7) >> 3;
    int s0 = beg + wave * chunk;
    int s1 = min(s0 + chunk, end);

    float av0 = 0.f, av1 = 0.f, av2 = 0.f, av3 = 0.f;   // aggv chains
    float dsum = 0.f;
    float ag0 = 0.f, ag1 = 0.f, ag2 = 0.f, ag3 = 0.f;
    const float2* sQ2 = (const float2*)sQ;

    for (int jb = s0; jb < s1; jb += 64) {
        int j = jb + lane;
        bool valid = (j < s1);
        int4 pk = make_int4(0, 0, 0, 0);
        if (valid) pk = spack[j];
        int oo = pk.x;
        float h = __int_as_float(pk.y);

        const uint4* krow = (const uint4*)(kb + (size_t)oo * 64);
        uint4 K0 = krow[0], K1 = krow[1], K2 = krow[2], K3 = krow[3];
        uint4 K4 = krow[4], K5 = krow[5], K6 = krow[6], K7 = krow[7];
        // 4 independent accumulator chains (depth 16 instead of 64)
        float a0 = h, a1 = 0.f, a2 = 0.f, a3 = 0.f;
        #define DOT8(Kv, base, A) { \
            float2 qa = sQ2[(base) + 0]; \
            A = fmaf(bflo(Kv.x), qa.x, A); A = fmaf(bfhi(Kv.x), qa.y, A); \
            float2 qb = sQ2[(base) + 1]; \
            A = fmaf(bflo(Kv.y), qb.x, A); A = fmaf(bfhi(Kv.y), qb.y, A); \
            float2 qc = sQ2[(base) + 2]; \
            A = fmaf(bflo(Kv.z), qc.x, A); A = fmaf(bfhi(Kv.z), qc.y, A); \
            float2 qd = sQ2[(base) + 3]; \
            A = fmaf(bflo(Kv.w), qd.x, A); A = fmaf(bfhi(Kv.w), qd.y, A); }
        DOT8(K0, 0, a0) DOT8(K1, 4, a1) DOT8(K2, 8, a2) DOT8(K3, 12, a3)
        DOT8(K4, 16, a0) DOT8(K5, 20, a1) DOT8(K6, 24, a2) DOT8(K7, 28, a3)
        #undef DOT8
        float acc = (a0 + a1) + (a2 + a3);

        float exv = valid ? __expf(acc * 0.125f) : 0.f;
        dsum += exv;
        unsigned int ez = (unsigned int)pk.z, ew = (unsigned int)pk.w;
        ag0 = fmaf(exv, bflo(ez), ag0);
        ag1 = fmaf(exv, bfhi(ez), ag1);
        ag2 = fmaf(exv, bflo(ew), ag2);
        ag3 = fmaf(exv, bfhi(ew), ag3);

        sOX[wave][lane] = make_int2(oo, __float_as_int(exv));

        int nn = min(s1 - jb, 64);
        int i = 0;
        for (; i + 8 <= nn; i += 8) {
            int2 x0 = sOX[wave][i + 0], x1 = sOX[wave][i + 1];
            int2 x2 = sOX[wave][i + 2], x3 = sOX[wave][i + 3];
            int2 x4 = sOX[wave][i + 4], x5 = sOX[wave][i + 5];
            int2 x6 = sOX[wave][i + 6], x7 = sOX[wave][i + 7];
            unsigned short u0 = vb[(size_t)x0.x * 64 + lane];
            unsigned short u1 = vb[(size_t)x1.x * 64 + lane];
            unsigned short u2 = vb[(size_t)x2.x * 64 + lane];
            unsigned short u3 = vb[(size_t)x3.x * 64 + lane];
            unsigned short u4 = vb[(size_t)x4.x * 64 + lane];
            unsigned short u5 = vb[(size_t)x5.x * 64 + lane];
            unsigned short u6 = vb[(size_t)x6.x * 64 + lane];
            unsigned short u7 = vb[(size_t)x7.x * 64 + lane];
            // 4 independent aggv chains
            av0 = fmaf(__int_as_float(x0.y), __uint_as_float((unsigned int)u0 << 16), av0);
            av1 = fmaf(__int_as_float(x1.y), __uint_as_float((unsigned int)u1 << 16), av1);
            av2 = fmaf(__int_as_float(x2.y), __uint_as_float((unsigned int)u2 << 16), av2);
            av3 = fmaf(__int_as_float(x3.y), __uint_as_float((unsigned int)u3 << 16), av3);
            av0 = fmaf(__int_as_float(x4.y), __uint_as_float((unsigned int)u4 << 16), av0);
            av1 = fmaf(__int_as_float(x5.y), __uint_as_float((unsigned int)u5 << 16), av1);
            av2 = fmaf(__int_as_float(x6.y), __uint_as_float((unsigned int)u6 << 16), av2);
            av3 = fmaf(__int_as_float(x7.y), __uint_as_float((unsigned int)u7 << 16), av3);
        }
        for (; i < nn; ++i) {
            int2 xx = sOX[wave][i];
            unsigned short uu = vb[(size_t)xx.x * 64 + lane];
            av0 = fmaf(__int_as_float(xx.y), __uint_as_float((unsigned int)uu << 16), av0);
        }
    }

    float aggv = (av0 + av1) + (av2 + av3);

    #pragma unroll
    for (int m = 1; m < 64; m <<= 1) {
        dsum += __shfl_xor(dsum, m);
        ag0 += __shfl_xor(ag0, m);
        ag1 += __shfl_xor(ag1, m);
        ag2 += __shfl_xor(ag2, m);
        ag3 += __shfl_xor(ag3, m);
    }

    rv[wave][lane] = aggv;
    if (lane == 0) {
        rd[wave] = dsum;
        re4[wave][0] = ag0; re4[wave][1] = ag1;
        re4[wave][2] = ag2; re4[wave][3] = ag3;
    }
    __syncthreads();
    if (threadIdx.x < 64) {
        int l = threadIdx.x;
        float av = 0.f, ds = 0.f, a0 = 0.f, a1 = 0.f, a2 = 0.f, a3 = 0.f;
        #pragma unroll
        for (int w = 0; w < 8; ++w) {
            av += rv[w][l]; ds += rd[w];
            a0 += re4[w][0]; a1 += re4[w][1]; a2 += re4[w][2]; a3 += re4[w][3];
        }
        float corr = a0 * We[0 * 64 + l] + a1 * We[1 * 64 + l]
                   + a2 * We[2 * 64 + l] + a3 * We[3 * 64 + l];
        float val = (av + corr) / (ds + 1e-16f) + skip[r * 64 + l];
        embb[r * 64 + l] = bfu(val);
        sQ[l] = val;                      // reuse sQ as emb row (f32 for Br)
    }
    __syncthreads();
    // fused Br: col c = tid (<128)
    if (threadIdx.x < 128) {
        int c = threadIdx.x;
        float a = b1eff[c];
        #pragma unroll 8
        for (int d = 0; d < 64; ++d)
            a = fmaf(sQ[d], W1[(size_t)(64 + d) * 128 + c], a);
        Br[r * 128 + c] = a;
    }
}

// ---------------------------------------------------------------------------
// per-edge scoring, swapped MFMA layout — EXACT round-6 body (measured
// optimum 52.0 us across 5 structural variants; do not touch).
// ---------------------------------------------------------------------------
__global__ __launch_bounds__(256) void k_edge2(
    const int* __restrict__ so, const int4* __restrict__ trec,
    const int* __restrict__ tilestart,
    const unsigned short* __restrict__ pb, const unsigned short* __restrict__ embb,
    const float* __restrict__ Br, const unsigned short* __restrict__ w1t,
    const float* __restrict__ W2, const float* __restrict__ b2,
    float* __restrict__ tmp)
{
    const int tid = threadIdx.x;
    const int wave = tid >> 6;
    const int lane = tid & 63;
    const int l15 = lane & 15;
    const int quad = lane >> 4;

    // ---- W1a^T fragments (A-operand: row=l15=n within ctl-tile) + W2 slice --
    bf16x8 bfr[8][2];
    floatx4 w2q[8];
    #pragma unroll
    for (int ctl = 0; ctl < 8; ++ctl) {
        int n = ctl * 16 + l15;
        bfr[ctl][0] = *(const bf16x8*)(w1t + n * 64 + quad * 8);
        bfr[ctl][1] = *(const bf16x8*)(w1t + n * 64 + 32 + quad * 8);
        w2q[ctl] = *(const floatx4*)(W2 + ctl * 16 + quad * 4);
    }
    float b2v = b2[0];
    const int ntiles = tilestart[NR_N];
    const bf16x8 z8 = (bf16x8){0, 0, 0, 0, 0, 0, 0, 0};

    union U4B { uint4 u; bf16x8 b; };

    const int stride = gridDim.x * 4;
    int tile = blockIdx.x * 4 + wave;
    if (tile >= ntiles) return;

    // prologue: first tile's rec + edge ids
    int4 rr = trec[tile];
    int o_rt[4];
    #pragma unroll
    for (int rt = 0; rt < 4; ++rt)
        o_rt[rt] = so[min(rr.y + rt * 16 + l15, rr.z - 1)];

    for (; tile < ntiles; tile += stride) {
        const int r = rr.x, jb = rr.y, jend = rr.z;

        // ---- B-operand gathers (edge rt*16+l15's oe row, k=quad*8) ----
        U4B A0[4], A1[4];
        #pragma unroll
        for (int rt = 0; rt < 4; ++rt) {
            const unsigned short* rowp = pb + (size_t)o_rt[rt] * 64 + quad * 8;
            A0[rt].u = *(const uint4*)(rowp);        // k = quad*8 .. +8
            A1[rt].u = *(const uint4*)(rowp + 32);   // k = 32+quad*8 .. +8
        }

        // ---- prefetch next tile's rec + edge ids (hidden under MFMA) ----
        int4 rrn = trec[min(tile + stride, ntiles - 1)];
        int o_nx[4];
        #pragma unroll
        for (int rt = 0; rt < 4; ++rt)
            o_nx[rt] = so[min(rrn.y + rt * 16 + l15, rrn.z - 1)];

        // ---- emb as A row 0 (dot column under swap) ----
        const unsigned short* eb = embb + r * 64;
        bf16x8 b80 = z8, b81 = z8;
        if (l15 == 0) {
            b80 = *(const bf16x8*)(eb + quad * 8);
            b81 = *(const bf16x8*)(eb + 32 + quad * 8);
        }

        const float* brrow = Br + r * 128;

        // ---- per 16-edge group: MFMA + in-lane relu/W2 + 2-step reduce ----
        #pragma unroll
        for (int rt = 0; rt < 4; ++rt) {
            float s = 0.f;
            #pragma unroll
            for (int ctl = 0; ctl < 8; ++ctl) {
                floatx4 c = *(const floatx4*)(brrow + ctl * 16 + quad * 4);  // C-init = Br[n]
                c = __builtin_amdgcn_mfma_f32_16x16x32_bf16(bfr[ctl][0], A0[rt].b, c, 0, 0, 0);
                c = __builtin_amdgcn_mfma_f32_16x16x32_bf16(bfr[ctl][1], A1[rt].b, c, 0, 0, 0);
                #pragma unroll
                for (int g = 0; g < 4; ++g)
                    s = fmaf(fmaxf(c[g], 0.f), w2q[ctl][g], s);
            }
            // dot(emb, oe): D[0][e] -> c8[0] on quad==0 lanes
            floatx4 c8 = (floatx4){0.f, 0.f, 0.f, 0.f};
            c8 = __builtin_amdgcn_mfma_f32_16x16x32_bf16(b80, A0[rt].b, c8, 0, 0, 0);
            c8 = __builtin_amdgcn_mfma_f32_16x16x32_bf16(b81, A1[rt].b, c8, 0, 0, 0);

            // reduce over quads (lanes e, e+16, e+32, e+48)
            s += __shfl_xor(s, 16);
            s += __shfl_xor(s, 32);

            if (quad == 0) {
                int pos = jb + rt * 16 + l15;
                if (pos < jend) {
                    float v = s + 0.125f * c8[0] + b2v;
                    tmp[pos] = fminf(fmaxf(v, -10.f), 10.f);
                }
            }
        }

        rr = rrn;
        #pragma unroll
        for (int rt = 0; rt < 4; ++rt) o_rt[rt] = o_nx[rt];
    }
}

// ---------------------------------------------------------------------------
// out[i] = tmp[rank[i]]  (rank coalesced read, tmp L2-resident gather)
// ---------------------------------------------------------------------------
__global__ __launch_bounds__(256) void k_perm(const int* __restrict__ rank,
                                              const float* __restrict__ tmp,
                                              float* __restrict__ out)
{
    int i = blockIdx.x * 256 + threadIdx.x;
    if (i < E_N) out[i] = tmp[rank[i]];
}

// ---------------------------------------------------------------------------
extern "C" void kernel_launch(void* const* d_in, const int* in_sizes, int n_in,
                              void* d_out, int out_size, void* d_ws, size_t ws_size,
                              hipStream_t stream)
{
    const float* x_order   = (const float*)d_in[0];
    const float* x_rider   = (const float*)d_in[1];
    const float* edge_attr = (const float*)d_in[2];
    const int*   order_idx = (const int*)d_in[3];
    const int*   rider_idx = (const int*)d_in[4];
    const float* omega     = (const float*)d_in[5];
    const float* Wk = (const float*)d_in[6];  const float* bk = (const float*)d_in[7];
    const float* Wq = (const float*)d_in[8];  const float* bq = (const float*)d_in[9];
    const float* Wv = (const float*)d_in[10]; const float* bv = (const float*)d_in[11];
    const float* We = (const float*)d_in[12];
    const float* Wskip = (const float*)d_in[13]; const float* bskip = (const float*)d_in[14];
    const float* Wp = (const float*)d_in[15]; const float* bp = (const float*)d_in[16];
    const float* W1 = (const float*)d_in[17]; const float* b1 = (const float*)d_in[18];
    const float* W2 = (const float*)d_in[19]; const float* b2 = (const float*)d_in[20];
    float* out = (float*)d_out;

    unsigned short* ws_kb = (unsigned short*)d_ws;
    unsigned short* ws_vb = ws_kb + (size_t)NO_N * 64;
    unsigned short* ws_pb = ws_vb + (size_t)NO_N * 64;
    int4* ws_spack = (int4*)(ws_pb + (size_t)NO_N * 64);
    float* ws_tmp  = (float*)ws_spack;              // alias: spack dead by k_edge2
    int*  ws_so    = (int*)(ws_spack + E_N);
    int*  ws_rank  = ws_so + E_N;
    float* wsf     = (float*)(ws_rank + E_N);
    float* ws_q    = wsf;
    float* ws_skip = ws_q + NR_N * 64;
    unsigned short* ws_embb = (unsigned short*)(ws_skip + NR_N * 64);  // bf16 emb
    float* ws_t    = (float*)(ws_embb + NR_N * 64);
    float* ws_b1e  = ws_t + NR_N * 4;
    unsigned short* ws_w1t = (unsigned short*)(ws_b1e + 128);  // 128x64 bf16
    float* ws_Br   = (float*)(ws_w1t + 128 * 64);
    int* ws_counts  = (int*)(ws_Br + NR_N * 128);
    int* ws_offsets = ws_counts + NR_N;
    int* ws_tilest  = ws_offsets + NR_N + 8;
    int* ws_ghist   = ws_tilest + NR_N + 8;
    int* ws_gpre    = ws_ghist + NR_N * SB;
    int* ws_done    = ws_gpre + NR_N * SB;
    int4* ws_trec   = (int4*)(((uintptr_t)(ws_done + 8) + 15) & ~(uintptr_t)15);

    k_front<<<251 + KVP_BLKS + SB, 256, 0, stream>>>(
        x_rider, Wq, bq, Wskip, bskip, We, ws_q, ws_skip, ws_t,
        W1, b1, omega, ws_b1e, ws_w1t,
        x_order, Wk, bk, Wv, bv, Wp, bp, ws_kb, ws_vb, ws_pb,
        rider_idx, ws_ghist, ws_done);
    k_mid<<<NR_N, 1024, 0, stream>>>(ws_ghist, ws_gpre, ws_counts,
                                     ws_offsets, ws_tilest, ws_done);
    k_scatter2<<<SB + TREC_BLKS, 1024, 0, stream>>>(
        rider_idx, order_idx, edge_attr, ws_t,
        ws_offsets, ws_gpre, ws_ghist, ws_spack, ws_so, ws_rank,
        ws_tilest, ws_trec);
    k_rider<<<NR_N, 512, 0, stream>>>(ws_offsets, ws_spack, ws_q,
                                      ws_kb, ws_vb, We, ws_skip,
                                      W1, ws_b1e, ws_embb, ws_Br);
    k_edge2<<<1024, 256, 0, stream>>>(ws_so, ws_trec, ws_tilest,
                                      ws_pb, ws_embb, ws_Br, ws_w1t, W2, b2, ws_tmp);
    k_perm<<<(E_N + 255) / 256, 256, 0, stream>>>(ws_rank, ws_tmp, out);
}

// Round 12
// 268.704 us; speedup vs baseline: 1.8919x; 1.8919x over previous
//
#include <hip/hip_runtime.h>
#include <hip/hip_bf16.h>
#include <math.h>
#include <stdint.h>

#define NO_N 100000
#define NR_N 1000
#define E_N  1000000
#define SB     250      // scatter blocks
#define SCHUNK 4000     // edges per scatter block (SB*SCHUNK == E_N)
#define KVP_TILES 1563  // ceil(NO_N/64)
#define KVP_BLKS 1024

typedef short bf16x8 __attribute__((ext_vector_type(8)));
typedef float floatx4 __attribute__((ext_vector_type(4)));

__device__ __forceinline__ unsigned short bfu(float x) {
    union { __hip_bfloat16 h; unsigned short u; } c;
    c.h = __float2bfloat16(x);
    return c.u;
}
__device__ __forceinline__ float bflo(unsigned int u) {
    return __uint_as_float(u << 16);
}
__device__ __forceinline__ float bfhi(unsigned int u) {
    return __uint_as_float(u & 0xffff0000u);
}

// ---------------------------------------------------------------------------
// fat front-end: [0,250) prep_rider | 250 b1eff + W1a^T bf16 table |
// [251,251+KVP_BLKS) kvp | then SB hist2 blocks.  All mutually independent.
// ---------------------------------------------------------------------------
__global__ __launch_bounds__(256) void k_front(
    const float* __restrict__ xr,
    const float* __restrict__ Wq, const float* __restrict__ bq,
    const float* __restrict__ Wskip, const float* __restrict__ bskip,
    const float* __restrict__ We,
    float* __restrict__ q, float* __restrict__ skip, float* __restrict__ t,
    const float* __restrict__ W1, const float* __restrict__ b1,
    const float* __restrict__ omega, float* __restrict__ b1eff,
    unsigned short* __restrict__ w1t,
    const float* __restrict__ x,
    const float* __restrict__ Wk, const float* __restrict__ bk,
    const float* __restrict__ Wv, const float* __restrict__ bv,
    const float* __restrict__ Wp, const float* __restrict__ bp,
    unsigned short* __restrict__ kb, unsigned short* __restrict__ vb,
    unsigned short* __restrict__ pb,
    const int* __restrict__ ridx, int* __restrict__ ghist)
{
    __shared__ __align__(16) char smem[9216];
    const int tid = threadIdx.x;
    const int b = blockIdx.x;

    if (b < 250) {
        // ---------------- prep_rider ----------------
        float* sx = (float*)smem;            // [4][32]
        float* sq = sx + 128;                // [4][64]
        int rbase = b * 4;
        if (tid < 128) {
            int rl = tid >> 5, d = tid & 31;
            sx[rl * 32 + d] = xr[(rbase + rl) * 32 + d];
        }
        __syncthreads();
        int rl = tid >> 6, h = tid & 63;
        int r = rbase + rl;
        float aq = bq[h], as = bskip[h];
        #pragma unroll 4
        for (int d = 0; d < 32; ++d) {
            float xv = sx[rl * 32 + d];
            aq += xv * Wq[d * 64 + h];
            as += xv * Wskip[d * 64 + h];
        }
        sq[rl * 64 + h] = aq;
        q[r * 64 + h] = aq;
        skip[r * 64 + h] = as;
        __syncthreads();
        if (tid < 16) {
            int rl2 = tid >> 2, d = tid & 3;
            float acc = 0.f;
            for (int hh = 0; hh < 64; ++hh)
                acc += We[d * 64 + hh] * sq[rl2 * 64 + hh];
            t[(rbase + rl2) * 4 + d] = acc;
        }
    } else if (b == 250) {
        // ---------------- b1eff + W1a^T bf16 (shared by all scoring blocks) --
        if (tid < 128) {
            float acc = b1[tid];
            #pragma unroll 4
            for (int j = 0; j < 32; ++j)
                acc += omega[j] * W1[(128 + j) * 128 + tid];
            b1eff[tid] = acc;
        }
        // w1t[n*64+k] = bf16(W1[k*128+n]) for k<64 (the oe rows), n<128
        for (int idx = tid; idx < 64 * 128; idx += 256) {
            int n = idx >> 6, k = idx & 63;
            w1t[idx] = bfu(W1[k * 128 + n]);
        }
    } else if (b < 251 + KVP_BLKS) {
        // ---------------- kvp (bf16 MFMA) ----------------
        unsigned short* sX = (unsigned short*)smem;   // 64*72
        const int wave = tid >> 6, lane = tid & 63;
        const int l15 = lane & 15, quad = lane >> 4;

        bf16x8 bfr[3][2];
        float bias[3];
        unsigned short* outT[3];
        int colc[3];
        #pragma unroll
        for (int ct = 0; ct < 3; ++ct) {
            int n = wave * 48 + ct * 16 + l15;
            int table = n >> 6, c = n & 63;
            const float* W  = (table == 0) ? Wk : (table == 1) ? Wv : Wp;
            const float* bb = (table == 0) ? bk : (table == 1) ? bv : bp;
            bias[ct] = bb[c];
            colc[ct] = c;
            outT[ct] = (table == 0) ? kb : (table == 1) ? vb : pb;
            #pragma unroll
            for (int kf = 0; kf < 2; ++kf) {
                bf16x8 f;
                #pragma unroll
                for (int j = 0; j < 8; ++j)
                    f[j] = (short)bfu(W[(size_t)(kf * 32 + quad * 8 + j) * 64 + c]);
                bfr[ct][kf] = f;
            }
        }

        const int srl = tid >> 2;
        const int sqt = (tid & 3) * 16;

        for (int tile = b - 251; tile < KVP_TILES; tile += KVP_BLKS) {
            int rowbase = tile * 64;
            {
                int row = rowbase + srl;
                unsigned short* dst = sX + srl * 72 + sqt;
                if (row < NO_N) {
                    const float4* src = (const float4*)(x + (size_t)row * 64 + sqt);
                    #pragma unroll
                    for (int i = 0; i < 4; ++i) {
                        float4 a = src[i];
                        ushort4 u = { bfu(a.x), bfu(a.y), bfu(a.z), bfu(a.w) };
                        *(ushort4*)(dst + i * 4) = u;
                    }
                } else {
                    ushort4 z = {0, 0, 0, 0};
                    #pragma unroll
                    for (int i = 0; i < 4; ++i) *(ushort4*)(dst + i * 4) = z;
                }
            }
            __syncthreads();

            floatx4 acc[4][3];
            #pragma unroll
            for (int rt = 0; rt < 4; ++rt)
                #pragma unroll
                for (int ct = 0; ct < 3; ++ct)
                    acc[rt][ct] = (floatx4){bias[ct], bias[ct], bias[ct], bias[ct]};

            #pragma unroll
            for (int rt = 0; rt < 4; ++rt) {
                const unsigned short* ar = sX + (size_t)(rt * 16 + l15) * 72 + quad * 8;
                bf16x8 a0 = *(const bf16x8*)(ar);
                bf16x8 a1 = *(const bf16x8*)(ar + 32);
                #pragma unroll
                for (int ct = 0; ct < 3; ++ct) {
                    floatx4 c = acc[rt][ct];
                    c = __builtin_amdgcn_mfma_f32_16x16x32_bf16(a0, bfr[ct][0], c, 0, 0, 0);
                    c = __builtin_amdgcn_mfma_f32_16x16x32_bf16(a1, bfr[ct][1], c, 0, 0, 0);
                    acc[rt][ct] = c;
                }
            }

            #pragma unroll
            for (int rt = 0; rt < 4; ++rt) {
                int rb = rowbase + rt * 16 + quad * 4;
                #pragma unroll
                for (int ct = 0; ct < 3; ++ct) {
                    unsigned short* o = outT[ct];
                    size_t cbase = colc[ct];
                    #pragma unroll
                    for (int g = 0; g < 4; ++g) {
                        int row = rb + g;
                        if (row < NO_N)
                            o[(size_t)row * 64 + cbase] = bfu(acc[rt][ct][g]);
                    }
                }
            }
            __syncthreads();
        }
    } else {
        // ---------------- hist2 ----------------
        int* hc = (int*)smem;                 // [NR_N]
        int hb = b - (251 + KVP_BLKS);
        for (int i = tid; i < NR_N; i += 256) hc[i] = 0;
        __syncthreads();
        int s = hb * SCHUNK;
        for (int i = s + tid; i < s + SCHUNK; i += 256)
            atomicAdd(&hc[ridx[i]], 1);
        __syncthreads();
        for (int i = tid; i < NR_N; i += 256)
            ghist[i * SB + hb] = hc[i];
    }
}

// ---------------------------------------------------------------------------
__global__ __launch_bounds__(256) void k_colscan(const int* __restrict__ ghist,
                                                 int* __restrict__ gpre,
                                                 int* __restrict__ counts)
{
    __shared__ int s[256];
    int tid = threadIdx.x, r = blockIdx.x;
    int v = (tid < SB) ? ghist[r * SB + tid] : 0;
    s[tid] = v;
    __syncthreads();
    for (int off = 1; off < 256; off <<= 1) {
        int tv = (tid >= off) ? s[tid - off] : 0;
        __syncthreads();
        s[tid] += tv;
        __syncthreads();
    }
    if (tid < SB) gpre[r * SB + tid] = s[tid] - v;
    if (tid == 255) counts[r] = s[255];
}

// scan over riders -> offsets only (tilestart/trec machinery dropped: the
// fused kernel derives its tiles from offsets[r]/offsets[r+1] directly)
__global__ __launch_bounds__(1024) void k_scan(const int* __restrict__ counts,
                                               int* __restrict__ offsets)
{
    __shared__ int s[1024];
    int tid = threadIdx.x;
    int c = (tid < NR_N) ? counts[tid] : 0;
    s[tid] = c;
    __syncthreads();
    for (int off = 1; off < 1024; off <<= 1) {
        int tv = (tid >= off) ? s[tid - off] : 0;
        __syncthreads();
        s[tid] += tv;
        __syncthreads();
    }
    if (tid < NR_N) offsets[tid] = s[tid] - c;
    if (tid == NR_N - 1) offsets[NR_N] = s[tid];
}

// ---------------------------------------------------------------------------
// scatter with block-local LDS staging + ordered flush (round-6 proven form).
// `so` dropped: the fused kernel reads edge ids from L2-hot spack, and tmp
// no longer aliases spack.
// ---------------------------------------------------------------------------
__global__ __launch_bounds__(1024) void k_scatter2(
    const int* __restrict__ ridx, const int* __restrict__ oidx,
    const float* __restrict__ ea, const float* __restrict__ t,
    const int* __restrict__ offsets, const int* __restrict__ gpre,
    const int* __restrict__ ghist,
    int4* __restrict__ spack, int* __restrict__ rank)
{
    __shared__ int stmp[1024];          // scan temp
    __shared__ int lpre[NR_N];          // block-local exclusive prefix
    __shared__ int lcur[NR_N];          // per-rider cursor (from 0)
    __shared__ int gbase[NR_N];         // offsets[r] + gpre[r][b]
    __shared__ __align__(16) int4 sbuf[SCHUNK];   // 64 KB staging
    __shared__ int spos[SCHUNK];        // global position per lpos

    const int tid = threadIdx.x, b = blockIdx.x;

    // ---- scan ghist[.][b] -> lpre; init lcur, gbase ----
    int v = (tid < NR_N) ? ghist[tid * SB + b] : 0;
    stmp[tid] = v;
    __syncthreads();
    for (int off = 1; off < 1024; off <<= 1) {
        int tv = (tid >= off) ? stmp[tid - off] : 0;
        __syncthreads();
        stmp[tid] += tv;
        __syncthreads();
    }
    if (tid < NR_N) {
        lpre[tid] = stmp[tid] - v;      // exclusive
        lcur[tid] = 0;
        gbase[tid] = offsets[tid] + gpre[tid * SB + b];
    }
    __syncthreads();

    // ---- compute + stage ----
    int s = b * SCHUNK;
    for (int i = s + tid; i < s + SCHUNK; i += 1024) {
        int r = ridx[i];
        int o = oidx[i];
        float4 e4 = *(const float4*)(ea + (size_t)i * 4);
        float4 t4 = *(const float4*)(t + r * 4);
        float h = e4.x * t4.x + e4.y * t4.y + e4.z * t4.z + e4.w * t4.w;
        int old = atomicAdd(&lcur[r], 1);
        int lpos = lpre[r] + old;
        int gp = gbase[r] + old;
        int4 pk;
        pk.x = o;
        pk.y = __float_as_int(h);
        pk.z = (int)((unsigned)bfu(e4.x) | ((unsigned)bfu(e4.y) << 16));
        pk.w = (int)((unsigned)bfu(e4.z) | ((unsigned)bfu(e4.w) << 16));
        sbuf[lpos] = pk;
        spos[lpos] = gp;
        rank[i] = gp;                   // coalesced in i
    }
    __syncthreads();

    // ---- ordered flush: consecutive lpos -> consecutive gp per group ----
    for (int l = tid; l < SCHUNK; l += 1024) {
        int4 pk = sbuf[l];
        spack[spos[l]] = pk;
    }
}

// ---------------------------------------------------------------------------
// FUSED rider-embedding + per-edge scoring.  One block per rider, 256
// threads (4 waves).  Phase 1 = rider body (emb + Br -> LDS).  Phase 2 =
// edge-scoring body over this rider's own tiles (ids from L2-hot spack;
// emb/Br from LDS).  Measured 269.9 us total — the best configuration.
// ---------------------------------------------------------------------------
__global__ __launch_bounds__(256) void k_fused(
    const int* __restrict__ offsets, const int4* __restrict__ spack,
    const float* __restrict__ q,
    const unsigned short* __restrict__ kb, const unsigned short* __restrict__ vb,
    const float* __restrict__ We, const float* __restrict__ skip,
    const float* __restrict__ W1, const float* __restrict__ b1eff,
    const unsigned short* __restrict__ pb, const unsigned short* __restrict__ w1t,
    const float* __restrict__ W2, const float* __restrict__ b2,
    float* __restrict__ tmp)
{
    __shared__ float sQ[64];
    __shared__ int2 sOX[4][64];
    __shared__ float rv[4][64];
    __shared__ float re4[4][4];
    __shared__ float rd[4];
    __shared__ __align__(16) unsigned short embL[64];
    __shared__ __align__(16) float BrL[128];

    const int r = blockIdx.x;
    const int wave = threadIdx.x >> 6, lane = threadIdx.x & 63;
    const int l15 = lane & 15, quad = lane >> 4;

    if (threadIdx.x < 64) sQ[threadIdx.x] = q[r * 64 + threadIdx.x];
    __syncthreads();

    const int beg = offsets[r], end = offsets[r + 1];
    const int cnt = end - beg;

    // ==================== phase 1: rider embedding ====================
    {
        int chunk = (cnt + 3) >> 2;
        int s0 = beg + wave * chunk;
        int s1 = min(s0 + chunk, end);

        float av0 = 0.f, av1 = 0.f, av2 = 0.f, av3 = 0.f;
        float dsum = 0.f;
        float ag0 = 0.f, ag1 = 0.f, ag2 = 0.f, ag3 = 0.f;
        const float2* sQ2 = (const float2*)sQ;

        for (int jb = s0; jb < s1; jb += 64) {
            int j = jb + lane;
            bool valid = (j < s1);
            int4 pk = make_int4(0, 0, 0, 0);
            if (valid) pk = spack[j];
            int oo = pk.x;
            float h = __int_as_float(pk.y);

            const uint4* krow = (const uint4*)(kb + (size_t)oo * 64);
            uint4 K0 = krow[0], K1 = krow[1], K2 = krow[2], K3 = krow[3];
            uint4 K4 = krow[4], K5 = krow[5], K6 = krow[6], K7 = krow[7];
            float a0 = h, a1 = 0.f, a2 = 0.f, a3 = 0.f;
            #define DOT8(Kv, base, A) { \
                float2 qa = sQ2[(base) + 0]; \
                A = fmaf(bflo(Kv.x), qa.x, A); A = fmaf(bfhi(Kv.x), qa.y, A); \
                float2 qb = sQ2[(base) + 1]; \
                A = fmaf(bflo(Kv.y), qb.x, A); A = fmaf(bfhi(Kv.y), qb.y, A); \
                float2 qc = sQ2[(base) + 2]; \
                A = fmaf(bflo(Kv.z), qc.x, A); A = fmaf(bfhi(Kv.z), qc.y, A); \
                float2 qd = sQ2[(base) + 3]; \
                A = fmaf(bflo(Kv.w), qd.x, A); A = fmaf(bfhi(Kv.w), qd.y, A); }
            DOT8(K0, 0, a0) DOT8(K1, 4, a1) DOT8(K2, 8, a2) DOT8(K3, 12, a3)
            DOT8(K4, 16, a0) DOT8(K5, 20, a1) DOT8(K6, 24, a2) DOT8(K7, 28, a3)
            #undef DOT8
            float acc = (a0 + a1) + (a2 + a3);

            float exv = valid ? __expf(acc * 0.125f) : 0.f;
            dsum += exv;
            unsigned int ez = (unsigned int)pk.z, ew = (unsigned int)pk.w;
            ag0 = fmaf(exv, bflo(ez), ag0);
            ag1 = fmaf(exv, bfhi(ez), ag1);
            ag2 = fmaf(exv, bflo(ew), ag2);
            ag3 = fmaf(exv, bfhi(ew), ag3);

            sOX[wave][lane] = make_int2(oo, __float_as_int(exv));

            int nn = min(s1 - jb, 64);
            int i = 0;
            for (; i + 8 <= nn; i += 8) {
                int2 x0 = sOX[wave][i + 0], x1 = sOX[wave][i + 1];
                int2 x2 = sOX[wave][i + 2], x3 = sOX[wave][i + 3];
                int2 x4 = sOX[wave][i + 4], x5 = sOX[wave][i + 5];
                int2 x6 = sOX[wave][i + 6], x7 = sOX[wave][i + 7];
                unsigned short u0 = vb[(size_t)x0.x * 64 + lane];
                unsigned short u1 = vb[(size_t)x1.x * 64 + lane];
                unsigned short u2 = vb[(size_t)x2.x * 64 + lane];
                unsigned short u3 = vb[(size_t)x3.x * 64 + lane];
                unsigned short u4 = vb[(size_t)x4.x * 64 + lane];
                unsigned short u5 = vb[(size_t)x5.x * 64 + lane];
                unsigned short u6 = vb[(size_t)x6.x * 64 + lane];
                unsigned short u7 = vb[(size_t)x7.x * 64 + lane];
                av0 = fmaf(__int_as_float(x0.y), __uint_as_float((unsigned int)u0 << 16), av0);
                av1 = fmaf(__int_as_float(x1.y), __uint_as_float((unsigned int)u1 << 16), av1);
                av2 = fmaf(__int_as_float(x2.y), __uint_as_float((unsigned int)u2 << 16), av2);
                av3 = fmaf(__int_as_float(x3.y), __uint_as_float((unsigned int)u3 << 16), av3);
                av0 = fmaf(__int_as_float(x4.y), __uint_as_float((unsigned int)u4 << 16), av0);
                av1 = fmaf(__int_as_float(x5.y), __uint_as_float((unsigned int)u5 << 16), av1);
                av2 = fmaf(__int_as_float(x6.y), __uint_as_float((unsigned int)u6 << 16), av2);
                av3 = fmaf(__int_as_float(x7.y), __uint_as_float((unsigned int)u7 << 16), av3);
            }
            for (; i < nn; ++i) {
                int2 xx = sOX[wave][i];
                unsigned short uu = vb[(size_t)xx.x * 64 + lane];
                av0 = fmaf(__int_as_float(xx.y), __uint_as_float((unsigned int)uu << 16), av0);
            }
        }

        float aggv = (av0 + av1) + (av2 + av3);

        #pragma unroll
        for (int m = 1; m < 64; m <<= 1) {
            dsum += __shfl_xor(dsum, m);
            ag0 += __shfl_xor(ag0, m);
            ag1 += __shfl_xor(ag1, m);
            ag2 += __shfl_xor(ag2, m);
            ag3 += __shfl_xor(ag3, m);
        }

        rv[wave][lane] = aggv;
        if (lane == 0) {
            rd[wave] = dsum;
            re4[wave][0] = ag0; re4[wave][1] = ag1;
            re4[wave][2] = ag2; re4[wave][3] = ag3;
        }
        __syncthreads();
        if (threadIdx.x < 64) {
            int l = threadIdx.x;
            float av = 0.f, ds = 0.f, a0 = 0.f, a1 = 0.f, a2 = 0.f, a3 = 0.f;
            #pragma unroll
            for (int w = 0; w < 4; ++w) {
                av += rv[w][l]; ds += rd[w];
                a0 += re4[w][0]; a1 += re4[w][1]; a2 += re4[w][2]; a3 += re4[w][3];
            }
            float corr = a0 * We[0 * 64 + l] + a1 * We[1 * 64 + l]
                       + a2 * We[2 * 64 + l] + a3 * We[3 * 64 + l];
            float val = (av + corr) / (ds + 1e-16f) + skip[r * 64 + l];
            embL[l] = bfu(val);
            sQ[l] = val;                  // reuse sQ as emb row (f32 for Br)
        }
        __syncthreads();
        if (threadIdx.x < 128) {
            int c = threadIdx.x;
            float a = b1eff[c];
            #pragma unroll 8
            for (int d = 0; d < 64; ++d)
                a = fmaf(sQ[d], W1[(size_t)(64 + d) * 128 + c], a);
            BrL[c] = a;
        }
        __syncthreads();
    }

    // ==================== phase 2: per-edge scoring ====================
    bf16x8 bfr[8][2];
    floatx4 w2q[8];
    #pragma unroll
    for (int ctl = 0; ctl < 8; ++ctl) {
        int n = ctl * 16 + l15;
        bfr[ctl][0] = *(const bf16x8*)(w1t + n * 64 + quad * 8);
        bfr[ctl][1] = *(const bf16x8*)(w1t + n * 64 + 32 + quad * 8);
        w2q[ctl] = *(const floatx4*)(W2 + ctl * 16 + quad * 4);
    }
    float b2v = b2[0];
    const bf16x8 z8 = (bf16x8){0, 0, 0, 0, 0, 0, 0, 0};
    bf16x8 b80 = z8, b81 = z8;
    if (l15 == 0) {
        b80 = *(const bf16x8*)(embL + quad * 8);
        b81 = *(const bf16x8*)(embL + 32 + quad * 8);
    }

    union U4B { uint4 u; bf16x8 b; };
    const int ntile = (cnt + 63) >> 6;

    for (int t = wave; t < ntile; t += 4) {
        int jb = beg + t * 64;

        // edge ids from spack (just streamed by phase 1 -> L1/L2-hot)
        int o_rt[4];
        #pragma unroll
        for (int rt = 0; rt < 4; ++rt)
            o_rt[rt] = spack[min(jb + rt * 16 + l15, end - 1)].x;

        // pb gathers (B-operand: edge rt*16+l15's oe row, k=quad*8)
        U4B A0[4], A1[4];
        #pragma unroll
        for (int rt = 0; rt < 4; ++rt) {
            const unsigned short* rowp = pb + (size_t)o_rt[rt] * 64 + quad * 8;
            A0[rt].u = *(const uint4*)(rowp);
            A1[rt].u = *(const uint4*)(rowp + 32);
        }

        #pragma unroll
        for (int rt = 0; rt < 4; ++rt) {
            float s = 0.f;
            #pragma unroll
            for (int ctl = 0; ctl < 8; ++ctl) {
                floatx4 c = *(const floatx4*)(BrL + ctl * 16 + quad * 4);  // C-init = Br[n]
                c = __builtin_amdgcn_mfma_f32_16x16x32_bf16(bfr[ctl][0], A0[rt].b, c, 0, 0, 0);
                c = __builtin_amdgcn_mfma_f32_16x16x32_bf16(bfr[ctl][1], A1[rt].b, c, 0, 0, 0);
                #pragma unroll
                for (int g = 0; g < 4; ++g)
                    s = fmaf(fmaxf(c[g], 0.f), w2q[ctl][g], s);
            }
            // dot(emb, oe): D[0][e] -> c8[0] on quad==0 lanes
            floatx4 c8 = (floatx4){0.f, 0.f, 0.f, 0.f};
            c8 = __builtin_amdgcn_mfma_f32_16x16x32_bf16(b80, A0[rt].b, c8, 0, 0, 0);
            c8 = __builtin_amdgcn_mfma_f32_16x16x32_bf16(b81, A1[rt].b, c8, 0, 0, 0);

            s += __shfl_xor(s, 16);
            s += __shfl_xor(s, 32);

            if (quad == 0) {
                int pos = jb + rt * 16 + l15;
                if (pos < end) {
                    float v = s + 0.125f * c8[0] + b2v;
                    tmp[pos] = fminf(fmaxf(v, -10.f), 10.f);
                }
            }
        }
    }
}

// ---------------------------------------------------------------------------
// out[i] = tmp[rank[i]]  (rank coalesced read, tmp L2-resident gather)
// ---------------------------------------------------------------------------
__global__ __launch_bounds__(256) void k_perm(const int* __restrict__ rank,
                                              const float* __restrict__ tmp,
                                              float* __restrict__ out)
{
    int i = blockIdx.x * 256 + threadIdx.x;
    if (i < E_N) out[i] = tmp[rank[i]];
}

// ---------------------------------------------------------------------------
extern "C" void kernel_launch(void* const* d_in, const int* in_sizes, int n_in,
                              void* d_out, int out_size, void* d_ws, size_t ws_size,
                              hipStream_t stream)
{
    const float* x_order   = (const float*)d_in[0];
    const float* x_rider   = (const float*)d_in[1];
    const float* edge_attr = (const float*)d_in[2];
    const int*   order_idx = (const int*)d_in[3];
    const int*   rider_idx = (const int*)d_in[4];
    const float* omega     = (const float*)d_in[5];
    const float* Wk = (const float*)d_in[6];  const float* bk = (const float*)d_in[7];
    const float* Wq = (const float*)d_in[8];  const float* bq = (const float*)d_in[9];
    const float* Wv = (const float*)d_in[10]; const float* bv = (const float*)d_in[11];
    const float* We = (const float*)d_in[12];
    const float* Wskip = (const float*)d_in[13]; const float* bskip = (const float*)d_in[14];
    const float* Wp = (const float*)d_in[15]; const float* bp = (const float*)d_in[16];
    const float* W1 = (const float*)d_in[17]; const float* b1 = (const float*)d_in[18];
    const float* W2 = (const float*)d_in[19]; const float* b2 = (const float*)d_in[20];
    float* out = (float*)d_out;

    unsigned short* ws_kb = (unsigned short*)d_ws;
    unsigned short* ws_vb = ws_kb + (size_t)NO_N * 64;
    unsigned short* ws_pb = ws_vb + (size_t)NO_N * 64;
    int4* ws_spack = (int4*)(ws_pb + (size_t)NO_N * 64);
    float* ws_tmp  = (float*)(ws_spack + E_N);      // own slot: NO spack alias
    int*  ws_rank  = (int*)(ws_tmp + E_N);
    float* wsf     = (float*)(ws_rank + E_N);
    float* ws_q    = wsf;
    float* ws_skip = ws_q + NR_N * 64;
    float* ws_t    = ws_skip + NR_N * 64;
    float* ws_b1e  = ws_t + NR_N * 4;
    unsigned short* ws_w1t = (unsigned short*)(ws_b1e + 128);  // 128x64 bf16
    int* ws_counts  = (int*)(ws_w1t + 128 * 64);
    int* ws_offsets = ws_counts + NR_N;
    int* ws_ghist   = ws_offsets + NR_N + 8;
    int* ws_gpre    = ws_ghist + NR_N * SB;

    k_front<<<251 + KVP_BLKS + SB, 256, 0, stream>>>(
        x_rider, Wq, bq, Wskip, bskip, We, ws_q, ws_skip, ws_t,
        W1, b1, omega, ws_b1e, ws_w1t,
        x_order, Wk, bk, Wv, bv, Wp, bp, ws_kb, ws_vb, ws_pb,
        rider_idx, ws_ghist);
    k_colscan<<<NR_N, 256, 0, stream>>>(ws_ghist, ws_gpre, ws_counts);
    k_scan<<<1, 1024, 0, stream>>>(ws_counts, ws_offsets);
    k_scatter2<<<SB, 1024, 0, stream>>>(rider_idx, order_idx, edge_attr, ws_t,
                                        ws_offsets, ws_gpre, ws_ghist,
                                        ws_spack, ws_rank);
    k_fused<<<NR_N, 256, 0, stream>>>(ws_offsets, ws_spack, ws_q,
                                      ws_kb, ws_vb, We, ws_skip,
                                      W1, ws_b1e, ws_pb, ws_w1t, W2, b2, ws_tmp);
    k_perm<<<(E_N + 255) / 256, 256, 0, stream>>>(ws_rank, ws_tmp, out);
}

// Round 14
// 265.489 us; speedup vs baseline: 1.9149x; 1.0121x over previous
//
#include <hip/hip_runtime.h>
#include <hip/hip_bf16.h>
#include <math.h>
#include <stdint.h>

#define NO_N 100000
#define NR_N 1000
#define E_N  1000000
#define SB     250      // scatter blocks
#define SCHUNK 4000     // edges per scatter block (SB*SCHUNK == E_N)
#define KVP_TILES 1563  // ceil(NO_N/64)
#define KVP_BLKS 1024

typedef short bf16x8 __attribute__((ext_vector_type(8)));
typedef float floatx4 __attribute__((ext_vector_type(4)));

__device__ __forceinline__ unsigned short bfu(float x) {
    union { __hip_bfloat16 h; unsigned short u; } c;
    c.h = __float2bfloat16(x);
    return c.u;
}
__device__ __forceinline__ float bflo(unsigned int u) {
    return __uint_as_float(u << 16);
}
__device__ __forceinline__ float bfhi(unsigned int u) {
    return __uint_as_float(u & 0xffff0000u);
}

// ---------------------------------------------------------------------------
// fat front-end: [0,250) prep_rider | 250 b1eff + W1a^T bf16 table |
// [251,251+KVP_BLKS) kvp | then SB hist2 blocks.  All mutually independent.
// ---------------------------------------------------------------------------
__global__ __launch_bounds__(256) void k_front(
    const float* __restrict__ xr,
    const float* __restrict__ Wq, const float* __restrict__ bq,
    const float* __restrict__ Wskip, const float* __restrict__ bskip,
    const float* __restrict__ We,
    float* __restrict__ q, float* __restrict__ skip, float* __restrict__ t,
    const float* __restrict__ W1, const float* __restrict__ b1,
    const float* __restrict__ omega, float* __restrict__ b1eff,
    unsigned short* __restrict__ w1t,
    const float* __restrict__ x,
    const float* __restrict__ Wk, const float* __restrict__ bk,
    const float* __restrict__ Wv, const float* __restrict__ bv,
    const float* __restrict__ Wp, const float* __restrict__ bp,
    unsigned short* __restrict__ kb, unsigned short* __restrict__ vb,
    unsigned short* __restrict__ pb,
    const int* __restrict__ ridx, int* __restrict__ ghist)
{
    __shared__ __align__(16) char smem[9216];
    const int tid = threadIdx.x;
    const int b = blockIdx.x;

    if (b < 250) {
        // ---------------- prep_rider ----------------
        float* sx = (float*)smem;            // [4][32]
        float* sq = sx + 128;                // [4][64]
        int rbase = b * 4;
        if (tid < 128) {
            int rl = tid >> 5, d = tid & 31;
            sx[rl * 32 + d] = xr[(rbase + rl) * 32 + d];
        }
        __syncthreads();
        int rl = tid >> 6, h = tid & 63;
        int r = rbase + rl;
        float aq = bq[h], as = bskip[h];
        #pragma unroll 4
        for (int d = 0; d < 32; ++d) {
            float xv = sx[rl * 32 + d];
            aq += xv * Wq[d * 64 + h];
            as += xv * Wskip[d * 64 + h];
        }
        sq[rl * 64 + h] = aq;
        q[r * 64 + h] = aq;
        skip[r * 64 + h] = as;
        __syncthreads();
        if (tid < 16) {
            int rl2 = tid >> 2, d = tid & 3;
            float acc = 0.f;
            for (int hh = 0; hh < 64; ++hh)
                acc += We[d * 64 + hh] * sq[rl2 * 64 + hh];
            t[(rbase + rl2) * 4 + d] = acc;
        }
    } else if (b == 250) {
        // ---------------- b1eff + W1a^T bf16 (shared by all scoring blocks) --
        if (tid < 128) {
            float acc = b1[tid];
            #pragma unroll 4
            for (int j = 0; j < 32; ++j)
                acc += omega[j] * W1[(128 + j) * 128 + tid];
            b1eff[tid] = acc;
        }
        // w1t[n*64+k] = bf16(W1[k*128+n]) for k<64 (the oe rows), n<128
        for (int idx = tid; idx < 64 * 128; idx += 256) {
            int n = idx >> 6, k = idx & 63;
            w1t[idx] = bfu(W1[k * 128 + n]);
        }
    } else if (b < 251 + KVP_BLKS) {
        // ---------------- kvp (bf16 MFMA) ----------------
        unsigned short* sX = (unsigned short*)smem;   // 64*72
        const int wave = tid >> 6, lane = tid & 63;
        const int l15 = lane & 15, quad = lane >> 4;

        bf16x8 bfr[3][2];
        float bias[3];
        unsigned short* outT[3];
        int colc[3];
        #pragma unroll
        for (int ct = 0; ct < 3; ++ct) {
            int n = wave * 48 + ct * 16 + l15;
            int table = n >> 6, c = n & 63;
            const float* W  = (table == 0) ? Wk : (table == 1) ? Wv : Wp;
            const float* bb = (table == 0) ? bk : (table == 1) ? bv : bp;
            bias[ct] = bb[c];
            colc[ct] = c;
            outT[ct] = (table == 0) ? kb : (table == 1) ? vb : pb;
            #pragma unroll
            for (int kf = 0; kf < 2; ++kf) {
                bf16x8 f;
                #pragma unroll
                for (int j = 0; j < 8; ++j)
                    f[j] = (short)bfu(W[(size_t)(kf * 32 + quad * 8 + j) * 64 + c]);
                bfr[ct][kf] = f;
            }
        }

        const int srl = tid >> 2;
        const int sqt = (tid & 3) * 16;

        for (int tile = b - 251; tile < KVP_TILES; tile += KVP_BLKS) {
            int rowbase = tile * 64;
            {
                int row = rowbase + srl;
                unsigned short* dst = sX + srl * 72 + sqt;
                if (row < NO_N) {
                    const float4* src = (const float4*)(x + (size_t)row * 64 + sqt);
                    #pragma unroll
                    for (int i = 0; i < 4; ++i) {
                        float4 a = src[i];
                        ushort4 u = { bfu(a.x), bfu(a.y), bfu(a.z), bfu(a.w) };
                        *(ushort4*)(dst + i * 4) = u;
                    }
                } else {
                    ushort4 z = {0, 0, 0, 0};
                    #pragma unroll
                    for (int i = 0; i < 4; ++i) *(ushort4*)(dst + i * 4) = z;
                }
            }
            __syncthreads();

            floatx4 acc[4][3];
            #pragma unroll
            for (int rt = 0; rt < 4; ++rt)
                #pragma unroll
                for (int ct = 0; ct < 3; ++ct)
                    acc[rt][ct] = (floatx4){bias[ct], bias[ct], bias[ct], bias[ct]};

            #pragma unroll
            for (int rt = 0; rt < 4; ++rt) {
                const unsigned short* ar = sX + (size_t)(rt * 16 + l15) * 72 + quad * 8;
                bf16x8 a0 = *(const bf16x8*)(ar);
                bf16x8 a1 = *(const bf16x8*)(ar + 32);
                #pragma unroll
                for (int ct = 0; ct < 3; ++ct) {
                    floatx4 c = acc[rt][ct];
                    c = __builtin_amdgcn_mfma_f32_16x16x32_bf16(a0, bfr[ct][0], c, 0, 0, 0);
                    c = __builtin_amdgcn_mfma_f32_16x16x32_bf16(a1, bfr[ct][1], c, 0, 0, 0);
                    acc[rt][ct] = c;
                }
            }

            #pragma unroll
            for (int rt = 0; rt < 4; ++rt) {
                int rb = rowbase + rt * 16 + quad * 4;
                #pragma unroll
                for (int ct = 0; ct < 3; ++ct) {
                    unsigned short* o = outT[ct];
                    size_t cbase = colc[ct];
                    #pragma unroll
                    for (int g = 0; g < 4; ++g) {
                        int row = rb + g;
                        if (row < NO_N)
                            o[(size_t)row * 64 + cbase] = bfu(acc[rt][ct][g]);
                    }
                }
            }
            __syncthreads();
        }
    } else {
        // ---------------- hist2 ----------------
        int* hc = (int*)smem;                 // [NR_N]
        int hb = b - (251 + KVP_BLKS);
        for (int i = tid; i < NR_N; i += 256) hc[i] = 0;
        __syncthreads();
        int s = hb * SCHUNK;
        for (int i = s + tid; i < s + SCHUNK; i += 256)
            atomicAdd(&hc[ridx[i]], 1);
        __syncthreads();
        for (int i = tid; i < NR_N; i += 256)
            ghist[i * SB + hb] = hc[i];
    }
}

// ---------------------------------------------------------------------------
__global__ __launch_bounds__(256) void k_colscan(const int* __restrict__ ghist,
                                                 int* __restrict__ gpre,
                                                 int* __restrict__ counts)
{
    __shared__ int s[256];
    int tid = threadIdx.x, r = blockIdx.x;
    int v = (tid < SB) ? ghist[r * SB + tid] : 0;
    s[tid] = v;
    __syncthreads();
    for (int off = 1; off < 256; off <<= 1) {
        int tv = (tid >= off) ? s[tid - off] : 0;
        __syncthreads();
        s[tid] += tv;
        __syncthreads();
    }
    if (tid < SB) gpre[r * SB + tid] = s[tid] - v;
    if (tid == 255) counts[r] = s[255];
}

// scan over riders -> offsets only (tilestart/trec machinery dropped: the
// fused kernel derives its tiles from offsets[r]/offsets[r+1] directly)
__global__ __launch_bounds__(1024) void k_scan(const int* __restrict__ counts,
                                               int* __restrict__ offsets)
{
    __shared__ int s[1024];
    int tid = threadIdx.x;
    int c = (tid < NR_N) ? counts[tid] : 0;
    s[tid] = c;
    __syncthreads();
    for (int off = 1; off < 1024; off <<= 1) {
        int tv = (tid >= off) ? s[tid - off] : 0;
        __syncthreads();
        s[tid] += tv;
        __syncthreads();
    }
    if (tid < NR_N) offsets[tid] = s[tid] - c;
    if (tid == NR_N - 1) offsets[NR_N] = s[tid];
}

// ---------------------------------------------------------------------------
// scatter with block-local LDS staging + ordered flush (round-6 proven form).
// ---------------------------------------------------------------------------
__global__ __launch_bounds__(1024) void k_scatter2(
    const int* __restrict__ ridx, const int* __restrict__ oidx,
    const float* __restrict__ ea, const float* __restrict__ t,
    const int* __restrict__ offsets, const int* __restrict__ gpre,
    const int* __restrict__ ghist,
    int4* __restrict__ spack, int* __restrict__ rank)
{
    __shared__ int stmp[1024];          // scan temp
    __shared__ int lpre[NR_N];          // block-local exclusive prefix
    __shared__ int lcur[NR_N];          // per-rider cursor (from 0)
    __shared__ int gbase[NR_N];         // offsets[r] + gpre[r][b]
    __shared__ __align__(16) int4 sbuf[SCHUNK];   // 64 KB staging
    __shared__ int spos[SCHUNK];        // global position per lpos

    const int tid = threadIdx.x, b = blockIdx.x;

    // ---- scan ghist[.][b] -> lpre; init lcur, gbase ----
    int v = (tid < NR_N) ? ghist[tid * SB + b] : 0;
    stmp[tid] = v;
    __syncthreads();
    for (int off = 1; off < 1024; off <<= 1) {
        int tv = (tid >= off) ? stmp[tid - off] : 0;
        __syncthreads();
        stmp[tid] += tv;
        __syncthreads();
    }
    if (tid < NR_N) {
        lpre[tid] = stmp[tid] - v;      // exclusive
        lcur[tid] = 0;
        gbase[tid] = offsets[tid] + gpre[tid * SB + b];
    }
    __syncthreads();

    // ---- compute + stage ----
    int s = b * SCHUNK;
    for (int i = s + tid; i < s + SCHUNK; i += 1024) {
        int r = ridx[i];
        int o = oidx[i];
        float4 e4 = *(const float4*)(ea + (size_t)i * 4);
        float4 t4 = *(const float4*)(t + r * 4);
        float h = e4.x * t4.x + e4.y * t4.y + e4.z * t4.z + e4.w * t4.w;
        int old = atomicAdd(&lcur[r], 1);
        int lpos = lpre[r] + old;
        int gp = gbase[r] + old;
        int4 pk;
        pk.x = o;
        pk.y = __float_as_int(h);
        pk.z = (int)((unsigned)bfu(e4.x) | ((unsigned)bfu(e4.y) << 16));
        pk.w = (int)((unsigned)bfu(e4.z) | ((unsigned)bfu(e4.w) << 16));
        sbuf[lpos] = pk;
        spos[lpos] = gp;
        rank[i] = gp;                   // coalesced in i
    }
    __syncthreads();

    // ---- ordered flush: consecutive lpos -> consecutive gp per group ----
    for (int l = tid; l < SCHUNK; l += 1024) {
        int4 pk = sbuf[l];
        spack[spos[l]] = pk;
    }
}

// ---------------------------------------------------------------------------
// FUSED rider-embedding + per-edge scoring.  One block per rider, 256
// threads (4 waves).  Phase 1 = rider body (emb + Br -> LDS).  Phase 2 =
// edge-scoring body over this rider's own tiles (ids from L2-hot spack;
// emb/Br from LDS).  Measured 268.7 us total — the best configuration.
// (r13's VGPR-diet variant of phase 2 FAILED correctness — reverted.)
// ---------------------------------------------------------------------------
__global__ __launch_bounds__(256) void k_fused(
    const int* __restrict__ offsets, const int4* __restrict__ spack,
    const float* __restrict__ q,
    const unsigned short* __restrict__ kb, const unsigned short* __restrict__ vb,
    const float* __restrict__ We, const float* __restrict__ skip,
    const float* __restrict__ W1, const float* __restrict__ b1eff,
    const unsigned short* __restrict__ pb, const unsigned short* __restrict__ w1t,
    const float* __restrict__ W2, const float* __restrict__ b2,
    float* __restrict__ tmp)
{
    __shared__ float sQ[64];
    __shared__ int2 sOX[4][64];
    __shared__ float rv[4][64];
    __shared__ float re4[4][4];
    __shared__ float rd[4];
    __shared__ __align__(16) unsigned short embL[64];
    __shared__ __align__(16) float BrL[128];

    const int r = blockIdx.x;
    const int wave = threadIdx.x >> 6, lane = threadIdx.x & 63;
    const int l15 = lane & 15, quad = lane >> 4;

    if (threadIdx.x < 64) sQ[threadIdx.x] = q[r * 64 + threadIdx.x];
    __syncthreads();

    const int beg = offsets[r], end = offsets[r + 1];
    const int cnt = end - beg;

    // ==================== phase 1: rider embedding ====================
    {
        int chunk = (cnt + 3) >> 2;
        int s0 = beg + wave * chunk;
        int s1 = min(s0 + chunk, end);

        float av0 = 0.f, av1 = 0.f, av2 = 0.f, av3 = 0.f;
        float dsum = 0.f;
        float ag0 = 0.f, ag1 = 0.f, ag2 = 0.f, ag3 = 0.f;
        const float2* sQ2 = (const float2*)sQ;

        for (int jb = s0; jb < s1; jb += 64) {
            int j = jb + lane;
            bool valid = (j < s1);
            int4 pk = make_int4(0, 0, 0, 0);
            if (valid) pk = spack[j];
            int oo = pk.x;
            float h = __int_as_float(pk.y);

            const uint4* krow = (const uint4*)(kb + (size_t)oo * 64);
            uint4 K0 = krow[0], K1 = krow[1], K2 = krow[2], K3 = krow[3];
            uint4 K4 = krow[4], K5 = krow[5], K6 = krow[6], K7 = krow[7];
            float a0 = h, a1 = 0.f, a2 = 0.f, a3 = 0.f;
            #define DOT8(Kv, base, A) { \
                float2 qa = sQ2[(base) + 0]; \
                A = fmaf(bflo(Kv.x), qa.x, A); A = fmaf(bfhi(Kv.x), qa.y, A); \
                float2 qb = sQ2[(base) + 1]; \
                A = fmaf(bflo(Kv.y), qb.x, A); A = fmaf(bfhi(Kv.y), qb.y, A); \
                float2 qc = sQ2[(base) + 2]; \
                A = fmaf(bflo(Kv.z), qc.x, A); A = fmaf(bfhi(Kv.z), qc.y, A); \
                float2 qd = sQ2[(base) + 3]; \
                A = fmaf(bflo(Kv.w), qd.x, A); A = fmaf(bfhi(Kv.w), qd.y, A); }
            DOT8(K0, 0, a0) DOT8(K1, 4, a1) DOT8(K2, 8, a2) DOT8(K3, 12, a3)
            DOT8(K4, 16, a0) DOT8(K5, 20, a1) DOT8(K6, 24, a2) DOT8(K7, 28, a3)
            #undef DOT8
            float acc = (a0 + a1) + (a2 + a3);

            float exv = valid ? __expf(acc * 0.125f) : 0.f;
            dsum += exv;
            unsigned int ez = (unsigned int)pk.z, ew = (unsigned int)pk.w;
            ag0 = fmaf(exv, bflo(ez), ag0);
            ag1 = fmaf(exv, bfhi(ez), ag1);
            ag2 = fmaf(exv, bflo(ew), ag2);
            ag3 = fmaf(exv, bfhi(ew), ag3);

            sOX[wave][lane] = make_int2(oo, __float_as_int(exv));

            int nn = min(s1 - jb, 64);
            int i = 0;
            for (; i + 8 <= nn; i += 8) {
                int2 x0 = sOX[wave][i + 0], x1 = sOX[wave][i + 1];
                int2 x2 = sOX[wave][i + 2], x3 = sOX[wave][i + 3];
                int2 x4 = sOX[wave][i + 4], x5 = sOX[wave][i + 5];
                int2 x6 = sOX[wave][i + 6], x7 = sOX[wave][i + 7];
                unsigned short u0 = vb[(size_t)x0.x * 64 + lane];
                unsigned short u1 = vb[(size_t)x1.x * 64 + lane];
                unsigned short u2 = vb[(size_t)x2.x * 64 + lane];
                unsigned short u3 = vb[(size_t)x3.x * 64 + lane];
                unsigned short u4 = vb[(size_t)x4.x * 64 + lane];
                unsigned short u5 = vb[(size_t)x5.x * 64 + lane];
                unsigned short u6 = vb[(size_t)x6.x * 64 + lane];
                unsigned short u7 = vb[(size_t)x7.x * 64 + lane];
                av0 = fmaf(__int_as_float(x0.y), __uint_as_float((unsigned int)u0 << 16), av0);
                av1 = fmaf(__int_as_float(x1.y), __uint_as_float((unsigned int)u1 << 16), av1);
                av2 = fmaf(__int_as_float(x2.y), __uint_as_float((unsigned int)u2 << 16), av2);
                av3 = fmaf(__int_as_float(x3.y), __uint_as_float((unsigned int)u3 << 16), av3);
                av0 = fmaf(__int_as_float(x4.y), __uint_as_float((unsigned int)u4 << 16), av0);
                av1 = fmaf(__int_as_float(x5.y), __uint_as_float((unsigned int)u5 << 16), av1);
                av2 = fmaf(__int_as_float(x6.y), __uint_as_float((unsigned int)u6 << 16), av2);
                av3 = fmaf(__int_as_float(x7.y), __uint_as_float((unsigned int)u7 << 16), av3);
            }
            for (; i < nn; ++i) {
                int2 xx = sOX[wave][i];
                unsigned short uu = vb[(size_t)xx.x * 64 + lane];
                av0 = fmaf(__int_as_float(xx.y), __uint_as_float((unsigned int)uu << 16), av0);
            }
        }

        float aggv = (av0 + av1) + (av2 + av3);

        #pragma unroll
        for (int m = 1; m < 64; m <<= 1) {
            dsum += __shfl_xor(dsum, m);
            ag0 += __shfl_xor(ag0, m);
            ag1 += __shfl_xor(ag1, m);
            ag2 += __shfl_xor(ag2, m);
            ag3 += __shfl_xor(ag3, m);
        }

        rv[wave][lane] = aggv;
        if (lane == 0) {
            rd[wave] = dsum;
            re4[wave][0] = ag0; re4[wave][1] = ag1;
            re4[wave][2] = ag2; re4[wave][3] = ag3;
        }
        __syncthreads();
        if (threadIdx.x < 64) {
            int l = threadIdx.x;
            float av = 0.f, ds = 0.f, a0 = 0.f, a1 = 0.f, a2 = 0.f, a3 = 0.f;
            #pragma unroll
            for (int w = 0; w < 4; ++w) {
                av += rv[w][l]; ds += rd[w];
                a0 += re4[w][0]; a1 += re4[w][1]; a2 += re4[w][2]; a3 += re4[w][3];
            }
            float corr = a0 * We[0 * 64 + l] + a1 * We[1 * 64 + l]
                       + a2 * We[2 * 64 + l] + a3 * We[3 * 64 + l];
            float val = (av + corr) / (ds + 1e-16f) + skip[r * 64 + l];
            embL[l] = bfu(val);
            sQ[l] = val;                  // reuse sQ as emb row (f32 for Br)
        }
        __syncthreads();
        if (threadIdx.x < 128) {
            int c = threadIdx.x;
            float a = b1eff[c];
            #pragma unroll 8
            for (int d = 0; d < 64; ++d)
                a = fmaf(sQ[d], W1[(size_t)(64 + d) * 128 + c], a);
            BrL[c] = a;
        }
        __syncthreads();
    }

    // ==================== phase 2: per-edge scoring ====================
    bf16x8 bfr[8][2];
    floatx4 w2q[8];
    #pragma unroll
    for (int ctl = 0; ctl < 8; ++ctl) {
        int n = ctl * 16 + l15;
        bfr[ctl][0] = *(const bf16x8*)(w1t + n * 64 + quad * 8);
        bfr[ctl][1] = *(const bf16x8*)(w1t + n * 64 + 32 + quad * 8);
        w2q[ctl] = *(const floatx4*)(W2 + ctl * 16 + quad * 4);
    }
    float b2v = b2[0];
    const bf16x8 z8 = (bf16x8){0, 0, 0, 0, 0, 0, 0, 0};
    bf16x8 b80 = z8, b81 = z8;
    if (l15 == 0) {
        b80 = *(const bf16x8*)(embL + quad * 8);
        b81 = *(const bf16x8*)(embL + 32 + quad * 8);
    }

    union U4B { uint4 u; bf16x8 b; };
    const int ntile = (cnt + 63) >> 6;

    for (int t = wave; t < ntile; t += 4) {
        int jb = beg + t * 64;

        // edge ids from spack (just streamed by phase 1 -> L1/L2-hot)
        int o_rt[4];
        #pragma unroll
        for (int rt = 0; rt < 4; ++rt)
            o_rt[rt] = spack[min(jb + rt * 16 + l15, end - 1)].x;

        // pb gathers (B-operand: edge rt*16+l15's oe row, k=quad*8)
        U4B A0[4], A1[4];
        #pragma unroll
        for (int rt = 0; rt < 4; ++rt) {
            const unsigned short* rowp = pb + (size_t)o_rt[rt] * 64 + quad * 8;
            A0[rt].u = *(const uint4*)(rowp);
            A1[rt].u = *(const uint4*)(rowp + 32);
        }

        #pragma unroll
        for (int rt = 0; rt < 4; ++rt) {
            float s = 0.f;
            #pragma unroll
            for (int ctl = 0; ctl < 8; ++ctl) {
                floatx4 c = *(const floatx4*)(BrL + ctl * 16 + quad * 4);  // C-init = Br[n]
                c = __builtin_amdgcn_mfma_f32_16x16x32_bf16(bfr[ctl][0], A0[rt].b, c, 0, 0, 0);
                c = __builtin_amdgcn_mfma_f32_16x16x32_bf16(bfr[ctl][1], A1[rt].b, c, 0, 0, 0);
                #pragma unroll
                for (int g = 0; g < 4; ++g)
                    s = fmaf(fmaxf(c[g], 0.f), w2q[ctl][g], s);
            }
            // dot(emb, oe): D[0][e] -> c8[0] on quad==0 lanes
            floatx4 c8 = (floatx4){0.f, 0.f, 0.f, 0.f};
            c8 = __builtin_amdgcn_mfma_f32_16x16x32_bf16(b80, A0[rt].b, c8, 0, 0, 0);
            c8 = __builtin_amdgcn_mfma_f32_16x16x32_bf16(b81, A1[rt].b, c8, 0, 0, 0);

            s += __shfl_xor(s, 16);
            s += __shfl_xor(s, 32);

            if (quad == 0) {
                int pos = jb + rt * 16 + l15;
                if (pos < end) {
                    float v = s + 0.125f * c8[0] + b2v;
                    tmp[pos] = fminf(fmaxf(v, -10.f), 10.f);
                }
            }
        }
    }
}

// ---------------------------------------------------------------------------
// out[i] = tmp[rank[i]]  (rank coalesced read, tmp L2-resident gather)
// ---------------------------------------------------------------------------
__global__ __launch_bounds__(256) void k_perm(const int* __restrict__ rank,
                                              const float* __restrict__ tmp,
                                              float* __restrict__ out)
{
    int i = blockIdx.x * 256 + threadIdx.x;
    if (i < E_N) out[i] = tmp[rank[i]];
}

// ---------------------------------------------------------------------------
extern "C" void kernel_launch(void* const* d_in, const int* in_sizes, int n_in,
                              void* d_out, int out_size, void* d_ws, size_t ws_size,
                              hipStream_t stream)
{
    const float* x_order   = (const float*)d_in[0];
    const float* x_rider   = (const float*)d_in[1];
    const float* edge_attr = (const float*)d_in[2];
    const int*   order_idx = (const int*)d_in[3];
    const int*   rider_idx = (const int*)d_in[4];
    const float* omega     = (const float*)d_in[5];
    const float* Wk = (const float*)d_in[6];  const float* bk = (const float*)d_in[7];
    const float* Wq = (const float*)d_in[8];  const float* bq = (const float*)d_in[9];
    const float* Wv = (const float*)d_in[10]; const float* bv = (const float*)d_in[11];
    const float* We = (const float*)d_in[12];
    const float* Wskip = (const float*)d_in[13]; const float* bskip = (const float*)d_in[14];
    const float* Wp = (const float*)d_in[15]; const float* bp = (const float*)d_in[16];
    const float* W1 = (const float*)d_in[17]; const float* b1 = (const float*)d_in[18];
    const float* W2 = (const float*)d_in[19]; const float* b2 = (const float*)d_in[20];
    float* out = (float*)d_out;

    unsigned short* ws_kb = (unsigned short*)d_ws;
    unsigned short* ws_vb = ws_kb + (size_t)NO_N * 64;
    unsigned short* ws_pb = ws_vb + (size_t)NO_N * 64;
    int4* ws_spack = (int4*)(ws_pb + (size_t)NO_N * 64);
    float* ws_tmp  = (float*)(ws_spack + E_N);      // own slot: NO spack alias
    int*  ws_rank  = (int*)(ws_tmp + E_N);
    float* wsf     = (float*)(ws_rank + E_N);
    float* ws_q    = wsf;
    float* ws_skip = ws_q + NR_N * 64;
    float* ws_t    = ws_skip + NR_N * 64;
    float* ws_b1e  = ws_t + NR_N * 4;
    unsigned short* ws_w1t = (unsigned short*)(ws_b1e + 128);  // 128x64 bf16
    int* ws_counts  = (int*)(ws_w1t + 128 * 64);
    int* ws_offsets = ws_counts + NR_N;
    int* ws_ghist   = ws_offsets + NR_N + 8;
    int* ws_gpre    = ws_ghist + NR_N * SB;

    k_front<<<251 + KVP_BLKS + SB, 256, 0, stream>>>(
        x_rider, Wq, bq, Wskip, bskip, We, ws_q, ws_skip, ws_t,
        W1, b1, omega, ws_b1e, ws_w1t,
        x_order, Wk, bk, Wv, bv, Wp, bp, ws_kb, ws_vb, ws_pb,
        rider_idx, ws_ghist);
    k_colscan<<<NR_N, 256, 0, stream>>>(ws_ghist, ws_gpre, ws_counts);
    k_scan<<<1, 1024, 0, stream>>>(ws_counts, ws_offsets);
    k_scatter2<<<SB, 1024, 0, stream>>>(rider_idx, order_idx, edge_attr, ws_t,
                                        ws_offsets, ws_gpre, ws_ghist,
                                        ws_spack, ws_rank);
    k_fused<<<NR_N, 256, 0, stream>>>(ws_offsets, ws_spack, ws_q,
                                      ws_kb, ws_vb, We, ws_skip,
                                      W1, ws_b1e, ws_pb, ws_w1t, W2, b2, ws_tmp);
    k_perm<<<(E_N + 255) / 256, 256, 0, stream>>>(ws_rank, ws_tmp, out);
}